// Round 3
// baseline (267.830 us; speedup 1.0000x reference)
//
#include <hip/hip_runtime.h>
#include <hip/hip_bf16.h>
#include <math.h>

// NNUE-style sparse feature transform + output head.
// One block (256 threads) per batch row. Two 128-thread halves split the
// segment's entries (even/odd) to halve the serial dependency chain; each
// half covers all 512 columns via float4. Entry loop unrolled x4 with
// grouped loads -> 16 float4 loads in flight per thread (latency hiding).
// Halves combined in LDS before the nonlinear (clip) epilogue.

constexpr int FT      = 512;
constexpr int FV      = 768;
constexpr int THREADS = 256;
constexpr int CHUNK   = 256;   // LDS staging chunk of segment entries

__global__ __launch_bounds__(THREADS)
void nnue_kernel(const float* __restrict__ values,
                 const float* __restrict__ W_ft,
                 const float* __restrict__ ft_b,
                 const float* __restrict__ W_fft,
                 const float* __restrict__ fft_b,
                 const float* __restrict__ W_out,
                 const float* __restrict__ out_b,
                 const int*   __restrict__ batch_ids,
                 const int*   __restrict__ stm_feat,
                 const int*   __restrict__ nstm_feat,
                 int nnz,
                 float* __restrict__ out)
{
    const int b   = blockIdx.x;
    const int t   = threadIdx.x;
    const int g   = t >> 7;        // half index: 0 or 1
    const int lt  = t & 127;       // lane within half
    const int col = lt * 4;

    // ---- segment bounds via lower_bound on sorted batch_ids ----
    int lo0 = 0, hi0 = nnz;
    while (lo0 < hi0) {
        int mid = (lo0 + hi0) >> 1;
        if (batch_ids[mid] < b) lo0 = mid + 1; else hi0 = mid;
    }
    int lo1 = lo0, hi1 = nnz;
    while (lo1 < hi1) {
        int mid = (lo1 + hi1) >> 1;
        if (batch_ids[mid] < b + 1) lo1 = mid + 1; else hi1 = mid;
    }
    const int seg_lo = lo0, seg_hi = lo1;

    __shared__ int   sh_off_s [CHUNK];
    __shared__ int   sh_off_sv[CHUNK];
    __shared__ int   sh_off_n [CHUNK];
    __shared__ int   sh_off_nv[CHUNK];
    __shared__ float sh_v     [CHUNK];
    __shared__ float4 sh_comb_s[FT / 4];   // half-1 partial acc (stm)
    __shared__ float4 sh_comb_n[FT / 4];   // half-1 partial acc (nstm)

    float4 acc_s = make_float4(0.f, 0.f, 0.f, 0.f);
    float4 acc_n = make_float4(0.f, 0.f, 0.f, 0.f);

    for (int base = seg_lo; base < seg_hi; base += CHUNK) {
        const int cnt = min(CHUNK, seg_hi - base);
        __syncthreads();
        if (t < cnt) {
            int fs = stm_feat[base + t];
            int fn = nstm_feat[base + t];
            sh_off_s [t] = fs * FT;
            sh_off_sv[t] = (fs % FV) * FT;
            sh_off_n [t] = fn * FT;
            sh_off_nv[t] = (fn % FV) * FT;
            sh_v     [t] = values[base + t];
        }
        __syncthreads();

        // this half handles entries j == g (mod 2); unroll 4 entries/iter
        int j = g;
        for (; j + 6 < cnt; j += 8) {
            const int j0 = j, j1 = j + 2, j2 = j + 4, j3 = j + 6;
            const float v0 = sh_v[j0], v1 = sh_v[j1], v2 = sh_v[j2], v3 = sh_v[j3];

            const float4 a0  = *(const float4*)(W_ft  + sh_off_s [j0] + col);
            const float4 av0 = *(const float4*)(W_fft + sh_off_sv[j0] + col);
            const float4 c0  = *(const float4*)(W_ft  + sh_off_n [j0] + col);
            const float4 cv0 = *(const float4*)(W_fft + sh_off_nv[j0] + col);
            const float4 a1  = *(const float4*)(W_ft  + sh_off_s [j1] + col);
            const float4 av1 = *(const float4*)(W_fft + sh_off_sv[j1] + col);
            const float4 c1  = *(const float4*)(W_ft  + sh_off_n [j1] + col);
            const float4 cv1 = *(const float4*)(W_fft + sh_off_nv[j1] + col);
            const float4 a2  = *(const float4*)(W_ft  + sh_off_s [j2] + col);
            const float4 av2 = *(const float4*)(W_fft + sh_off_sv[j2] + col);
            const float4 c2  = *(const float4*)(W_ft  + sh_off_n [j2] + col);
            const float4 cv2 = *(const float4*)(W_fft + sh_off_nv[j2] + col);
            const float4 a3  = *(const float4*)(W_ft  + sh_off_s [j3] + col);
            const float4 av3 = *(const float4*)(W_fft + sh_off_sv[j3] + col);
            const float4 c3  = *(const float4*)(W_ft  + sh_off_n [j3] + col);
            const float4 cv3 = *(const float4*)(W_fft + sh_off_nv[j3] + col);

            acc_s.x = fmaf(a0.x + av0.x, v0, acc_s.x);
            acc_s.y = fmaf(a0.y + av0.y, v0, acc_s.y);
            acc_s.z = fmaf(a0.z + av0.z, v0, acc_s.z);
            acc_s.w = fmaf(a0.w + av0.w, v0, acc_s.w);
            acc_n.x = fmaf(c0.x + cv0.x, v0, acc_n.x);
            acc_n.y = fmaf(c0.y + cv0.y, v0, acc_n.y);
            acc_n.z = fmaf(c0.z + cv0.z, v0, acc_n.z);
            acc_n.w = fmaf(c0.w + cv0.w, v0, acc_n.w);

            acc_s.x = fmaf(a1.x + av1.x, v1, acc_s.x);
            acc_s.y = fmaf(a1.y + av1.y, v1, acc_s.y);
            acc_s.z = fmaf(a1.z + av1.z, v1, acc_s.z);
            acc_s.w = fmaf(a1.w + av1.w, v1, acc_s.w);
            acc_n.x = fmaf(c1.x + cv1.x, v1, acc_n.x);
            acc_n.y = fmaf(c1.y + cv1.y, v1, acc_n.y);
            acc_n.z = fmaf(c1.z + cv1.z, v1, acc_n.z);
            acc_n.w = fmaf(c1.w + cv1.w, v1, acc_n.w);

            acc_s.x = fmaf(a2.x + av2.x, v2, acc_s.x);
            acc_s.y = fmaf(a2.y + av2.y, v2, acc_s.y);
            acc_s.z = fmaf(a2.z + av2.z, v2, acc_s.z);
            acc_s.w = fmaf(a2.w + av2.w, v2, acc_s.w);
            acc_n.x = fmaf(c2.x + cv2.x, v2, acc_n.x);
            acc_n.y = fmaf(c2.y + cv2.y, v2, acc_n.y);
            acc_n.z = fmaf(c2.z + cv2.z, v2, acc_n.z);
            acc_n.w = fmaf(c2.w + cv2.w, v2, acc_n.w);

            acc_s.x = fmaf(a3.x + av3.x, v3, acc_s.x);
            acc_s.y = fmaf(a3.y + av3.y, v3, acc_s.y);
            acc_s.z = fmaf(a3.z + av3.z, v3, acc_s.z);
            acc_s.w = fmaf(a3.w + av3.w, v3, acc_s.w);
            acc_n.x = fmaf(c3.x + cv3.x, v3, acc_n.x);
            acc_n.y = fmaf(c3.y + cv3.y, v3, acc_n.y);
            acc_n.z = fmaf(c3.z + cv3.z, v3, acc_n.z);
            acc_n.w = fmaf(c3.w + cv3.w, v3, acc_n.w);
        }
        for (; j < cnt; j += 2) {
            const float v0 = sh_v[j];
            const float4 a  = *(const float4*)(W_ft  + sh_off_s [j] + col);
            const float4 av = *(const float4*)(W_fft + sh_off_sv[j] + col);
            const float4 c  = *(const float4*)(W_ft  + sh_off_n [j] + col);
            const float4 cv = *(const float4*)(W_fft + sh_off_nv[j] + col);
            acc_s.x = fmaf(a.x + av.x, v0, acc_s.x);
            acc_s.y = fmaf(a.y + av.y, v0, acc_s.y);
            acc_s.z = fmaf(a.z + av.z, v0, acc_s.z);
            acc_s.w = fmaf(a.w + av.w, v0, acc_s.w);
            acc_n.x = fmaf(c.x + cv.x, v0, acc_n.x);
            acc_n.y = fmaf(c.y + cv.y, v0, acc_n.y);
            acc_n.z = fmaf(c.z + cv.z, v0, acc_n.z);
            acc_n.w = fmaf(c.w + cv.w, v0, acc_n.w);
        }
    }

    // ---- combine the two halves in LDS ----
    __syncthreads();
    if (g == 1) {
        sh_comb_s[lt] = acc_s;
        sh_comb_n[lt] = acc_n;
    }
    __syncthreads();

    float partial = 0.f;
    if (g == 0) {
        const float4 os = sh_comb_s[lt];
        const float4 on = sh_comb_n[lt];
        acc_s.x += os.x; acc_s.y += os.y; acc_s.z += os.z; acc_s.w += os.w;
        acc_n.x += on.x; acc_n.y += on.y; acc_n.z += on.z; acc_n.w += on.w;

        const float4 fb  = *(const float4*)(ft_b  + col);
        const float4 vb  = *(const float4*)(fft_b + col);
        const float4 wos = *(const float4*)(W_out + col);
        const float4 won = *(const float4*)(W_out + FT + col);

        float h;
        h = fminf(fmaxf(acc_s.x + fb.x + vb.x, 0.f), 1.f); partial = fmaf(h, wos.x, partial);
        h = fminf(fmaxf(acc_s.y + fb.y + vb.y, 0.f), 1.f); partial = fmaf(h, wos.y, partial);
        h = fminf(fmaxf(acc_s.z + fb.z + vb.z, 0.f), 1.f); partial = fmaf(h, wos.z, partial);
        h = fminf(fmaxf(acc_s.w + fb.w + vb.w, 0.f), 1.f); partial = fmaf(h, wos.w, partial);
        h = fminf(fmaxf(acc_n.x + fb.x + vb.x, 0.f), 1.f); partial = fmaf(h, won.x, partial);
        h = fminf(fmaxf(acc_n.y + fb.y + vb.y, 0.f), 1.f); partial = fmaf(h, won.y, partial);
        h = fminf(fmaxf(acc_n.z + fb.z + vb.z, 0.f), 1.f); partial = fmaf(h, won.z, partial);
        h = fminf(fmaxf(acc_n.w + fb.w + vb.w, 0.f), 1.f); partial = fmaf(h, won.w, partial);
    }

    // wave (64-lane) shuffle reduction across all 4 waves (waves 2,3 add 0)
    #pragma unroll
    for (int off = 32; off > 0; off >>= 1)
        partial += __shfl_down(partial, off, 64);

    __shared__ float wave_sum[THREADS / 64];
    if ((t & 63) == 0) wave_sum[t >> 6] = partial;
    __syncthreads();
    if (t == 0) {
        float s = wave_sum[0] + wave_sum[1] + wave_sum[2] + wave_sum[3] + out_b[0];
        out[b] = 1.0f / (1.0f + expf(-s));
    }
}

extern "C" void kernel_launch(void* const* d_in, const int* in_sizes, int n_in,
                              void* d_out, int out_size, void* d_ws, size_t ws_size,
                              hipStream_t stream) {
    const float* values    = (const float*)d_in[0];
    const float* W_ft      = (const float*)d_in[1];
    const float* ft_b      = (const float*)d_in[2];
    const float* W_fft     = (const float*)d_in[3];
    const float* fft_b     = (const float*)d_in[4];
    const float* W_out     = (const float*)d_in[5];
    const float* out_b     = (const float*)d_in[6];
    const int*   batch_ids = (const int*)d_in[7];
    const int*   stm_feat  = (const int*)d_in[8];
    const int*   nstm_feat = (const int*)d_in[9];

    const int nnz = in_sizes[0];
    const int B   = out_size;   // (B,1) f32 output

    nnue_kernel<<<B, THREADS, 0, stream>>>(
        values, W_ft, ft_b, W_fft, fft_b, W_out, out_b,
        batch_ids, stm_feat, nstm_feat, nnz, (float*)d_out);
}

// Round 4
// 236.709 us; speedup vs baseline: 1.1315x; 1.1315x over previous
//
#include <hip/hip_runtime.h>
#include <hip/hip_bf16.h>
#include <math.h>

// NNUE-style sparse feature transform + output head.
// Round 4: bf16-compressed weight tables (prepass into d_ws) to halve gather
// bytes. Main kernel: one 128-thread block per batch row; the two waves split
// the segment's entries (even/odd) with NO inner-loop barrier; each lane
// covers 8 columns with one 16B ushort8 load per table per side.
// f32 fallback kernel if ws_size is too small for the bf16 tables.

constexpr int FT      = 512;
constexpr int FV      = 768;
constexpr int THREADS = 128;
constexpr int CHUNK   = 128;

typedef __attribute__((ext_vector_type(8))) unsigned short ushort8_t;

__device__ inline unsigned short f2bf(float x) {     // RNE f32 -> bf16 bits
    union { float f; unsigned int u; } v; v.f = x;
    unsigned int r = v.u + 0x7FFFu + ((v.u >> 16) & 1u);
    return (unsigned short)(r >> 16);
}
__device__ inline float bf2f(unsigned short s) {     // bf16 bits -> f32
    union { unsigned int u; float f; } v; v.u = ((unsigned int)s) << 16;
    return v.f;
}

// ---------------- prepass: f32 tables -> bf16 in workspace ----------------
__global__ __launch_bounds__(256)
void convert_kernel(const float* __restrict__ W_ft, const float* __restrict__ W_fft,
                    unsigned short* __restrict__ ft_bf, unsigned short* __restrict__ fft_bf,
                    int n8_ft, int n8_total)
{
    int i = blockIdx.x * 256 + threadIdx.x;   // index in 8-float groups
    if (i >= n8_total) return;
    const float* src; unsigned short* dst; int base;
    if (i < n8_ft) { src = W_ft;  dst = ft_bf;  base = i * 8; }
    else           { src = W_fft; dst = fft_bf; base = (i - n8_ft) * 8; }
    const float4 f0 = *(const float4*)(src + base);
    const float4 f1 = *(const float4*)(src + base + 4);
    ushort8_t u;
    u[0] = f2bf(f0.x); u[1] = f2bf(f0.y); u[2] = f2bf(f0.z); u[3] = f2bf(f0.w);
    u[4] = f2bf(f1.x); u[5] = f2bf(f1.y); u[6] = f2bf(f1.z); u[7] = f2bf(f1.w);
    *(ushort8_t*)(dst + base) = u;
}

// ---------------- main kernel: bf16 gather ----------------
__global__ __launch_bounds__(THREADS)
void nnue_bf16_kernel(const float* __restrict__ values,
                      const unsigned short* __restrict__ Wft,
                      const float* __restrict__ ft_b,
                      const unsigned short* __restrict__ Wfft,
                      const float* __restrict__ fft_b,
                      const float* __restrict__ W_out,
                      const float* __restrict__ out_b,
                      const int*   __restrict__ batch_ids,
                      const int*   __restrict__ stm_feat,
                      const int*   __restrict__ nstm_feat,
                      int nnz,
                      float* __restrict__ out)
{
    const int b    = blockIdx.x;
    const int t    = threadIdx.x;
    const int w    = t >> 6;       // wave 0 / 1
    const int lane = t & 63;
    const int col  = lane * 8;     // 8 columns per lane

    // segment bounds (sorted batch_ids) — broadcast binary search
    int lo0 = 0, hi0 = nnz;
    while (lo0 < hi0) {
        int mid = (lo0 + hi0) >> 1;
        if (batch_ids[mid] < b) lo0 = mid + 1; else hi0 = mid;
    }
    int lo1 = lo0, hi1 = nnz;
    while (lo1 < hi1) {
        int mid = (lo1 + hi1) >> 1;
        if (batch_ids[mid] < b + 1) lo1 = mid + 1; else hi1 = mid;
    }
    const int seg_lo = lo0, seg_hi = lo1;

    __shared__ int   sh_off_s [CHUNK];
    __shared__ int   sh_off_sv[CHUNK];
    __shared__ int   sh_off_n [CHUNK];
    __shared__ int   sh_off_nv[CHUNK];
    __shared__ float sh_v     [CHUNK];
    __shared__ float sh_comb  [2][FT];   // wave-1 partials (stm, nstm)

    float acc_s[8] = {0,0,0,0,0,0,0,0};
    float acc_n[8] = {0,0,0,0,0,0,0,0};

    for (int base = seg_lo; base < seg_hi; base += CHUNK) {
        const int cnt = min(CHUNK, seg_hi - base);
        __syncthreads();
        if (t < cnt) {
            int fs = stm_feat[base + t];
            int fn = nstm_feat[base + t];
            sh_off_s [t] = fs * FT;
            sh_off_sv[t] = (fs % FV) * FT;
            sh_off_n [t] = fn * FT;
            sh_off_nv[t] = (fn % FV) * FT;
            sh_v     [t] = values[base + t];
        }
        __syncthreads();

        // this wave handles entries j == w (mod 2); simple body, let the
        // compiler software-pipeline (R3 lesson: manual grouping hurts)
        #pragma unroll 4
        for (int j = w; j < cnt; j += 2) {
            const float v = sh_v[j];
            const ushort8_t a  = *(const ushort8_t*)(Wft  + sh_off_s [j] + col);
            const ushort8_t av = *(const ushort8_t*)(Wfft + sh_off_sv[j] + col);
            const ushort8_t c  = *(const ushort8_t*)(Wft  + sh_off_n [j] + col);
            const ushort8_t cv = *(const ushort8_t*)(Wfft + sh_off_nv[j] + col);
            #pragma unroll
            for (int k = 0; k < 8; ++k) {
                acc_s[k] = fmaf(bf2f(a[k]) + bf2f(av[k]), v, acc_s[k]);
                acc_n[k] = fmaf(bf2f(c[k]) + bf2f(cv[k]), v, acc_n[k]);
            }
        }
    }

    // combine the two waves' partials through LDS
    __syncthreads();
    if (w == 1) {
        #pragma unroll
        for (int k = 0; k < 8; ++k) {
            sh_comb[0][col + k] = acc_s[k];
            sh_comb[1][col + k] = acc_n[k];
        }
    }
    __syncthreads();

    if (w == 0) {
        #pragma unroll
        for (int k = 0; k < 8; ++k) {
            acc_s[k] += sh_comb[0][col + k];
            acc_n[k] += sh_comb[1][col + k];
        }

        const float4 fb0 = *(const float4*)(ft_b  + col);
        const float4 fb1 = *(const float4*)(ft_b  + col + 4);
        const float4 vb0 = *(const float4*)(fft_b + col);
        const float4 vb1 = *(const float4*)(fft_b + col + 4);
        const float4 ws0 = *(const float4*)(W_out + col);
        const float4 ws1 = *(const float4*)(W_out + col + 4);
        const float4 wn0 = *(const float4*)(W_out + FT + col);
        const float4 wn1 = *(const float4*)(W_out + FT + col + 4);

        const float bias[8] = { fb0.x + vb0.x, fb0.y + vb0.y, fb0.z + vb0.z, fb0.w + vb0.w,
                                fb1.x + vb1.x, fb1.y + vb1.y, fb1.z + vb1.z, fb1.w + vb1.w };
        const float wos[8]  = { ws0.x, ws0.y, ws0.z, ws0.w, ws1.x, ws1.y, ws1.z, ws1.w };
        const float won[8]  = { wn0.x, wn0.y, wn0.z, wn0.w, wn1.x, wn1.y, wn1.z, wn1.w };

        float partial = 0.f;
        #pragma unroll
        for (int k = 0; k < 8; ++k) {
            float hs = fminf(fmaxf(acc_s[k] + bias[k], 0.f), 1.f);
            float hn = fminf(fmaxf(acc_n[k] + bias[k], 0.f), 1.f);
            partial = fmaf(hs, wos[k], partial);
            partial = fmaf(hn, won[k], partial);
        }

        #pragma unroll
        for (int off = 32; off > 0; off >>= 1)
            partial += __shfl_down(partial, off, 64);

        if (lane == 0)
            out[b] = 1.0f / (1.0f + expf(-(partial + out_b[0])));
    }
}

// ---------------- f32 fallback (Round-2 kernel) if ws too small ----------------
__global__ __launch_bounds__(THREADS)
void nnue_f32_kernel(const float* __restrict__ values,
                     const float* __restrict__ W_ft,
                     const float* __restrict__ ft_b,
                     const float* __restrict__ W_fft,
                     const float* __restrict__ fft_b,
                     const float* __restrict__ W_out,
                     const float* __restrict__ out_b,
                     const int*   __restrict__ batch_ids,
                     const int*   __restrict__ stm_feat,
                     const int*   __restrict__ nstm_feat,
                     int nnz,
                     float* __restrict__ out)
{
    const int b   = blockIdx.x;
    const int t   = threadIdx.x;
    const int col = t * 4;

    int lo0 = 0, hi0 = nnz;
    while (lo0 < hi0) {
        int mid = (lo0 + hi0) >> 1;
        if (batch_ids[mid] < b) lo0 = mid + 1; else hi0 = mid;
    }
    int lo1 = lo0, hi1 = nnz;
    while (lo1 < hi1) {
        int mid = (lo1 + hi1) >> 1;
        if (batch_ids[mid] < b + 1) lo1 = mid + 1; else hi1 = mid;
    }
    const int seg_lo = lo0, seg_hi = lo1;

    __shared__ int   sh_off_s [CHUNK];
    __shared__ int   sh_off_sv[CHUNK];
    __shared__ int   sh_off_n [CHUNK];
    __shared__ int   sh_off_nv[CHUNK];
    __shared__ float sh_v     [CHUNK];

    float4 acc_s = make_float4(0.f, 0.f, 0.f, 0.f);
    float4 acc_n = make_float4(0.f, 0.f, 0.f, 0.f);

    for (int base = seg_lo; base < seg_hi; base += CHUNK) {
        const int cnt = min(CHUNK, seg_hi - base);
        __syncthreads();
        if (t < cnt) {
            int fs = stm_feat[base + t];
            int fn = nstm_feat[base + t];
            sh_off_s [t] = fs * FT;
            sh_off_sv[t] = (fs % FV) * FT;
            sh_off_n [t] = fn * FT;
            sh_off_nv[t] = (fn % FV) * FT;
            sh_v     [t] = values[base + t];
        }
        __syncthreads();

        #pragma unroll 2
        for (int j = 0; j < cnt; ++j) {
            const float v = sh_v[j];
            const float4 a  = *(const float4*)(W_ft  + sh_off_s [j] + col);
            const float4 av = *(const float4*)(W_fft + sh_off_sv[j] + col);
            const float4 c  = *(const float4*)(W_ft  + sh_off_n [j] + col);
            const float4 cv = *(const float4*)(W_fft + sh_off_nv[j] + col);
            acc_s.x = fmaf(a.x + av.x, v, acc_s.x);
            acc_s.y = fmaf(a.y + av.y, v, acc_s.y);
            acc_s.z = fmaf(a.z + av.z, v, acc_s.z);
            acc_s.w = fmaf(a.w + av.w, v, acc_s.w);
            acc_n.x = fmaf(c.x + cv.x, v, acc_n.x);
            acc_n.y = fmaf(c.y + cv.y, v, acc_n.y);
            acc_n.z = fmaf(c.z + cv.z, v, acc_n.z);
            acc_n.w = fmaf(c.w + cv.w, v, acc_n.w);
        }
    }

    const float4 fb  = *(const float4*)(ft_b  + col);
    const float4 vb  = *(const float4*)(fft_b + col);
    const float4 wos = *(const float4*)(W_out + col);
    const float4 won = *(const float4*)(W_out + FT + col);

    float partial = 0.f;
    {
        float h;
        h = fminf(fmaxf(acc_s.x + fb.x + vb.x, 0.f), 1.f); partial = fmaf(h, wos.x, partial);
        h = fminf(fmaxf(acc_s.y + fb.y + vb.y, 0.f), 1.f); partial = fmaf(h, wos.y, partial);
        h = fminf(fmaxf(acc_s.z + fb.z + vb.z, 0.f), 1.f); partial = fmaf(h, wos.z, partial);
        h = fminf(fmaxf(acc_s.w + fb.w + vb.w, 0.f), 1.f); partial = fmaf(h, wos.w, partial);
        h = fminf(fmaxf(acc_n.x + fb.x + vb.x, 0.f), 1.f); partial = fmaf(h, won.x, partial);
        h = fminf(fmaxf(acc_n.y + fb.y + vb.y, 0.f), 1.f); partial = fmaf(h, won.y, partial);
        h = fminf(fmaxf(acc_n.z + fb.z + vb.z, 0.f), 1.f); partial = fmaf(h, won.z, partial);
        h = fminf(fmaxf(acc_n.w + fb.w + vb.w, 0.f), 1.f); partial = fmaf(h, won.w, partial);
    }

    #pragma unroll
    for (int off = 32; off > 0; off >>= 1)
        partial += __shfl_down(partial, off, 64);

    __shared__ float wave_sum[THREADS / 64];
    if ((t & 63) == 0) wave_sum[t >> 6] = partial;
    __syncthreads();
    if (t == 0) {
        float s = wave_sum[0] + wave_sum[1] + out_b[0];
        out[b] = 1.0f / (1.0f + expf(-s));
    }
}

extern "C" void kernel_launch(void* const* d_in, const int* in_sizes, int n_in,
                              void* d_out, int out_size, void* d_ws, size_t ws_size,
                              hipStream_t stream) {
    const float* values    = (const float*)d_in[0];
    const float* W_ft      = (const float*)d_in[1];
    const float* ft_b      = (const float*)d_in[2];
    const float* W_fft     = (const float*)d_in[3];
    const float* fft_b     = (const float*)d_in[4];
    const float* W_out     = (const float*)d_in[5];
    const float* out_b     = (const float*)d_in[6];
    const int*   batch_ids = (const int*)d_in[7];
    const int*   stm_feat  = (const int*)d_in[8];
    const int*   nstm_feat = (const int*)d_in[9];

    const int nnz    = in_sizes[0];
    const int B      = out_size;
    const int n_ft   = in_sizes[1];   // F_FULL*FT
    const int n_fft  = in_sizes[3];   // F_VIRT*FT

    const size_t need = (size_t)(n_ft + n_fft) * sizeof(unsigned short);

    if (ws_size >= need) {
        unsigned short* ft_bf  = (unsigned short*)d_ws;
        unsigned short* fft_bf = ft_bf + n_ft;
        const int n8_ft    = n_ft / 8;
        const int n8_total = (n_ft + n_fft) / 8;
        const int cgrid    = (n8_total + 255) / 256;
        convert_kernel<<<cgrid, 256, 0, stream>>>(W_ft, W_fft, ft_bf, fft_bf,
                                                  n8_ft, n8_total);
        nnue_bf16_kernel<<<B, THREADS, 0, stream>>>(
            values, ft_bf, ft_b, fft_bf, fft_b, W_out, out_b,
            batch_ids, stm_feat, nstm_feat, nnz, (float*)d_out);
    } else {
        nnue_f32_kernel<<<B, THREADS, 0, stream>>>(
            values, W_ft, ft_b, W_fft, fft_b, W_out, out_b,
            batch_ids, stm_feat, nstm_feat, nnz, (float*)d_out);
    }
}

// Round 5
// 230.178 us; speedup vs baseline: 1.1636x; 1.0284x over previous
//
#include <hip/hip_runtime.h>
#include <hip/hip_bf16.h>
#include <math.h>

// NNUE-style sparse feature transform + output head.
// Round 5: COMBINED bf16 table in workspace: W_comb[f] = W_ft[f] + W_fft[f%768].
// Reference's two segment_sums over W_ft[feat] and W_fft[feat%768] are
// algebraically one segment_sum over the combined row (we already computed
// (a+av)*v in-loop), so the gather needs ONE row per feature per side:
// 2 ushort8 loads per entry instead of 4, half the logical traffic and
// half the inner-loop VALU. Convert prepass cost is unchanged.
// Main kernel: 128 threads/block, one block per batch row, two waves split
// entries even/odd with no inner-loop barrier (R2/R4-proven shape).

constexpr int FT      = 512;
constexpr int FV      = 768;
constexpr int THREADS = 128;
constexpr int CHUNK   = 128;

typedef __attribute__((ext_vector_type(8))) unsigned short ushort8_t;

__device__ inline unsigned short f2bf(float x) {     // RNE f32 -> bf16 bits
    union { float f; unsigned int u; } v; v.f = x;
    unsigned int r = v.u + 0x7FFFu + ((v.u >> 16) & 1u);
    return (unsigned short)(r >> 16);
}
__device__ inline float bf2f(unsigned short s) {     // bf16 bits -> f32
    union { unsigned int u; float f; } v; v.u = ((unsigned int)s) << 16;
    return v.f;
}

// ---- prepass: W_comb[f][c] = bf16(W_ft[f][c] + W_fft[f%768][c]) ----
__global__ __launch_bounds__(256)
void convert_kernel(const float* __restrict__ W_ft, const float* __restrict__ W_fft,
                    unsigned short* __restrict__ comb, int n8)
{
    int i = blockIdx.x * 256 + threadIdx.x;   // 8-element group index
    if (i >= n8) return;
    const int f    = i >> 6;                  // 64 groups of 8 per 512-col row
    const int gcol = (i & 63) * 8;
    const int base = i * 8;
    const int vrow = (f % FV) * FT + gcol;

    const float4 a0 = *(const float4*)(W_ft  + base);
    const float4 a1 = *(const float4*)(W_ft  + base + 4);
    const float4 b0 = *(const float4*)(W_fft + vrow);
    const float4 b1 = *(const float4*)(W_fft + vrow + 4);

    ushort8_t u;
    u[0] = f2bf(a0.x + b0.x); u[1] = f2bf(a0.y + b0.y);
    u[2] = f2bf(a0.z + b0.z); u[3] = f2bf(a0.w + b0.w);
    u[4] = f2bf(a1.x + b1.x); u[5] = f2bf(a1.y + b1.y);
    u[6] = f2bf(a1.z + b1.z); u[7] = f2bf(a1.w + b1.w);
    *(ushort8_t*)(comb + base) = u;
}

// ---- main kernel: combined-table bf16 gather ----
__global__ __launch_bounds__(THREADS)
void nnue_comb_kernel(const float* __restrict__ values,
                      const unsigned short* __restrict__ Wc,
                      const float* __restrict__ ft_b,
                      const float* __restrict__ fft_b,
                      const float* __restrict__ W_out,
                      const float* __restrict__ out_b,
                      const int*   __restrict__ batch_ids,
                      const int*   __restrict__ stm_feat,
                      const int*   __restrict__ nstm_feat,
                      int nnz,
                      float* __restrict__ out)
{
    const int b    = blockIdx.x;
    const int t    = threadIdx.x;
    const int w    = t >> 6;       // wave 0 / 1
    const int lane = t & 63;
    const int col  = lane * 8;     // 8 columns per lane

    // segment bounds (sorted batch_ids) — broadcast binary search
    int lo0 = 0, hi0 = nnz;
    while (lo0 < hi0) {
        int mid = (lo0 + hi0) >> 1;
        if (batch_ids[mid] < b) lo0 = mid + 1; else hi0 = mid;
    }
    int lo1 = lo0, hi1 = nnz;
    while (lo1 < hi1) {
        int mid = (lo1 + hi1) >> 1;
        if (batch_ids[mid] < b + 1) lo1 = mid + 1; else hi1 = mid;
    }
    const int seg_lo = lo0, seg_hi = lo1;

    __shared__ int   sh_off_s[CHUNK];
    __shared__ int   sh_off_n[CHUNK];
    __shared__ float sh_v    [CHUNK];
    __shared__ float sh_comb [2][FT];   // wave-1 partials (stm, nstm)

    float acc_s[8] = {0,0,0,0,0,0,0,0};
    float acc_n[8] = {0,0,0,0,0,0,0,0};

    for (int base = seg_lo; base < seg_hi; base += CHUNK) {
        const int cnt = min(CHUNK, seg_hi - base);
        __syncthreads();
        if (t < cnt) {
            sh_off_s[t] = stm_feat [base + t] * FT;
            sh_off_n[t] = nstm_feat[base + t] * FT;
            sh_v    [t] = values[base + t];
        }
        __syncthreads();

        // this wave handles entries j == w (mod 2); simple body (R3 lesson)
        #pragma unroll 4
        for (int j = w; j < cnt; j += 2) {
            const float v = sh_v[j];
            const ushort8_t a = *(const ushort8_t*)(Wc + sh_off_s[j] + col);
            const ushort8_t c = *(const ushort8_t*)(Wc + sh_off_n[j] + col);
            #pragma unroll
            for (int k = 0; k < 8; ++k) {
                acc_s[k] = fmaf(bf2f(a[k]), v, acc_s[k]);
                acc_n[k] = fmaf(bf2f(c[k]), v, acc_n[k]);
            }
        }
    }

    // combine the two waves' partials through LDS
    __syncthreads();
    if (w == 1) {
        #pragma unroll
        for (int k = 0; k < 8; ++k) {
            sh_comb[0][col + k] = acc_s[k];
            sh_comb[1][col + k] = acc_n[k];
        }
    }
    __syncthreads();

    if (w == 0) {
        #pragma unroll
        for (int k = 0; k < 8; ++k) {
            acc_s[k] += sh_comb[0][col + k];
            acc_n[k] += sh_comb[1][col + k];
        }

        const float4 fb0 = *(const float4*)(ft_b  + col);
        const float4 fb1 = *(const float4*)(ft_b  + col + 4);
        const float4 vb0 = *(const float4*)(fft_b + col);
        const float4 vb1 = *(const float4*)(fft_b + col + 4);
        const float4 ws0 = *(const float4*)(W_out + col);
        const float4 ws1 = *(const float4*)(W_out + col + 4);
        const float4 wn0 = *(const float4*)(W_out + FT + col);
        const float4 wn1 = *(const float4*)(W_out + FT + col + 4);

        const float bias[8] = { fb0.x + vb0.x, fb0.y + vb0.y, fb0.z + vb0.z, fb0.w + vb0.w,
                                fb1.x + vb1.x, fb1.y + vb1.y, fb1.z + vb1.z, fb1.w + vb1.w };
        const float wos[8]  = { ws0.x, ws0.y, ws0.z, ws0.w, ws1.x, ws1.y, ws1.z, ws1.w };
        const float won[8]  = { wn0.x, wn0.y, wn0.z, wn0.w, wn1.x, wn1.y, wn1.z, wn1.w };

        float partial = 0.f;
        #pragma unroll
        for (int k = 0; k < 8; ++k) {
            float hs = fminf(fmaxf(acc_s[k] + bias[k], 0.f), 1.f);
            float hn = fminf(fmaxf(acc_n[k] + bias[k], 0.f), 1.f);
            partial = fmaf(hs, wos[k], partial);
            partial = fmaf(hn, won[k], partial);
        }

        #pragma unroll
        for (int off = 32; off > 0; off >>= 1)
            partial += __shfl_down(partial, off, 64);

        if (lane == 0)
            out[b] = 1.0f / (1.0f + expf(-(partial + out_b[0])));
    }
}

// ---- f32 fallback (Round-2 kernel) if ws too small ----
__global__ __launch_bounds__(THREADS)
void nnue_f32_kernel(const float* __restrict__ values,
                     const float* __restrict__ W_ft,
                     const float* __restrict__ ft_b,
                     const float* __restrict__ W_fft,
                     const float* __restrict__ fft_b,
                     const float* __restrict__ W_out,
                     const float* __restrict__ out_b,
                     const int*   __restrict__ batch_ids,
                     const int*   __restrict__ stm_feat,
                     const int*   __restrict__ nstm_feat,
                     int nnz,
                     float* __restrict__ out)
{
    const int b   = blockIdx.x;
    const int t   = threadIdx.x;
    const int col = t * 4;

    int lo0 = 0, hi0 = nnz;
    while (lo0 < hi0) {
        int mid = (lo0 + hi0) >> 1;
        if (batch_ids[mid] < b) lo0 = mid + 1; else hi0 = mid;
    }
    int lo1 = lo0, hi1 = nnz;
    while (lo1 < hi1) {
        int mid = (lo1 + hi1) >> 1;
        if (batch_ids[mid] < b + 1) lo1 = mid + 1; else hi1 = mid;
    }
    const int seg_lo = lo0, seg_hi = lo1;

    __shared__ int   sh_off_s [CHUNK];
    __shared__ int   sh_off_sv[CHUNK];
    __shared__ int   sh_off_n [CHUNK];
    __shared__ int   sh_off_nv[CHUNK];
    __shared__ float sh_v     [CHUNK];

    float4 acc_s = make_float4(0.f, 0.f, 0.f, 0.f);
    float4 acc_n = make_float4(0.f, 0.f, 0.f, 0.f);

    for (int base = seg_lo; base < seg_hi; base += CHUNK) {
        const int cnt = min(CHUNK, seg_hi - base);
        __syncthreads();
        if (t < cnt) {
            int fs = stm_feat[base + t];
            int fn = nstm_feat[base + t];
            sh_off_s [t] = fs * FT;
            sh_off_sv[t] = (fs % FV) * FT;
            sh_off_n [t] = fn * FT;
            sh_off_nv[t] = (fn % FV) * FT;
            sh_v     [t] = values[base + t];
        }
        __syncthreads();

        #pragma unroll 2
        for (int j = 0; j < cnt; ++j) {
            const float v = sh_v[j];
            const float4 a  = *(const float4*)(W_ft  + sh_off_s [j] + col);
            const float4 av = *(const float4*)(W_fft + sh_off_sv[j] + col);
            const float4 c  = *(const float4*)(W_ft  + sh_off_n [j] + col);
            const float4 cv = *(const float4*)(W_fft + sh_off_nv[j] + col);
            acc_s.x = fmaf(a.x + av.x, v, acc_s.x);
            acc_s.y = fmaf(a.y + av.y, v, acc_s.y);
            acc_s.z = fmaf(a.z + av.z, v, acc_s.z);
            acc_s.w = fmaf(a.w + av.w, v, acc_s.w);
            acc_n.x = fmaf(c.x + cv.x, v, acc_n.x);
            acc_n.y = fmaf(c.y + cv.y, v, acc_n.y);
            acc_n.z = fmaf(c.z + cv.z, v, acc_n.z);
            acc_n.w = fmaf(c.w + cv.w, v, acc_n.w);
        }
    }

    const float4 fb  = *(const float4*)(ft_b  + col);
    const float4 vb  = *(const float4*)(fft_b + col);
    const float4 wos = *(const float4*)(W_out + col);
    const float4 won = *(const float4*)(W_out + FT + col);

    float partial = 0.f;
    {
        float h;
        h = fminf(fmaxf(acc_s.x + fb.x + vb.x, 0.f), 1.f); partial = fmaf(h, wos.x, partial);
        h = fminf(fmaxf(acc_s.y + fb.y + vb.y, 0.f), 1.f); partial = fmaf(h, wos.y, partial);
        h = fminf(fmaxf(acc_s.z + fb.z + vb.z, 0.f), 1.f); partial = fmaf(h, wos.z, partial);
        h = fminf(fmaxf(acc_s.w + fb.w + vb.w, 0.f), 1.f); partial = fmaf(h, wos.w, partial);
        h = fminf(fmaxf(acc_n.x + fb.x + vb.x, 0.f), 1.f); partial = fmaf(h, won.x, partial);
        h = fminf(fmaxf(acc_n.y + fb.y + vb.y, 0.f), 1.f); partial = fmaf(h, won.y, partial);
        h = fminf(fmaxf(acc_n.z + fb.z + vb.z, 0.f), 1.f); partial = fmaf(h, won.z, partial);
        h = fminf(fmaxf(acc_n.w + fb.w + vb.w, 0.f), 1.f); partial = fmaf(h, won.w, partial);
    }

    #pragma unroll
    for (int off = 32; off > 0; off >>= 1)
        partial += __shfl_down(partial, off, 64);

    __shared__ float wave_sum[THREADS / 64];
    if ((t & 63) == 0) wave_sum[t >> 6] = partial;
    __syncthreads();
    if (t == 0) {
        float s = wave_sum[0] + wave_sum[1] + out_b[0];
        out[b] = 1.0f / (1.0f + expf(-s));
    }
}

extern "C" void kernel_launch(void* const* d_in, const int* in_sizes, int n_in,
                              void* d_out, int out_size, void* d_ws, size_t ws_size,
                              hipStream_t stream) {
    const float* values    = (const float*)d_in[0];
    const float* W_ft      = (const float*)d_in[1];
    const float* ft_b      = (const float*)d_in[2];
    const float* W_fft     = (const float*)d_in[3];
    const float* fft_b     = (const float*)d_in[4];
    const float* W_out     = (const float*)d_in[5];
    const float* out_b     = (const float*)d_in[6];
    const int*   batch_ids = (const int*)d_in[7];
    const int*   stm_feat  = (const int*)d_in[8];
    const int*   nstm_feat = (const int*)d_in[9];

    const int nnz  = in_sizes[0];
    const int B    = out_size;
    const int n_ft = in_sizes[1];   // F_FULL*FT elements

    const size_t need = (size_t)n_ft * sizeof(unsigned short);

    if (ws_size >= need) {
        unsigned short* comb = (unsigned short*)d_ws;
        const int n8    = n_ft / 8;
        const int cgrid = (n8 + 255) / 256;
        convert_kernel<<<cgrid, 256, 0, stream>>>(W_ft, W_fft, comb, n8);
        nnue_comb_kernel<<<B, THREADS, 0, stream>>>(
            values, comb, ft_b, fft_b, W_out, out_b,
            batch_ids, stm_feat, nstm_feat, nnz, (float*)d_out);
    } else {
        nnue_f32_kernel<<<B, THREADS, 0, stream>>>(
            values, W_ft, ft_b, W_fft, fft_b, W_out, out_b,
            batch_ids, stm_feat, nstm_feat, nnz, (float*)d_out);
    }
}

// Round 6
// 217.967 us; speedup vs baseline: 1.2288x; 1.0560x over previous
//
#include <hip/hip_runtime.h>
#include <hip/hip_bf16.h>
#include <math.h>

// NNUE-style sparse feature transform + output head.
// Round 6: hoist segment-bound binary searches into a prepass.
// R5 counters showed the gather kernel is serial-latency-bound: 2x17
// dependent batch_ids loads (~13k cyc) dominated each block's critical path.
// bounds_kernel computes seg_start[0..B] once (8193 parallel searches, ~2us);
// the gather kernel then reads 2 uniform ints. Loop body unchanged from R5.

constexpr int FT      = 512;
constexpr int FV      = 768;
constexpr int THREADS = 128;
constexpr int CHUNK   = 128;

typedef __attribute__((ext_vector_type(8))) unsigned short ushort8_t;

__device__ inline unsigned short f2bf(float x) {     // RNE f32 -> bf16 bits
    union { float f; unsigned int u; } v; v.f = x;
    unsigned int r = v.u + 0x7FFFu + ((v.u >> 16) & 1u);
    return (unsigned short)(r >> 16);
}
__device__ inline float bf2f(unsigned short s) {     // bf16 bits -> f32
    union { unsigned int u; float f; } v; v.u = ((unsigned int)s) << 16;
    return v.f;
}

// ---- prepass 1: seg_start[b] = lower_bound(batch_ids, b), b in [0, B] ----
__global__ __launch_bounds__(256)
void bounds_kernel(const int* __restrict__ batch_ids, int nnz, int B,
                   int* __restrict__ seg_start)
{
    int b = blockIdx.x * 256 + threadIdx.x;
    if (b > B) return;
    int lo = 0, hi = nnz;
    while (lo < hi) {
        int mid = (lo + hi) >> 1;
        if (batch_ids[mid] < b) lo = mid + 1; else hi = mid;
    }
    seg_start[b] = lo;
}

// ---- prepass 2: W_comb[f][c] = bf16(W_ft[f][c] + W_fft[f%768][c]) ----
__global__ __launch_bounds__(256)
void convert_kernel(const float* __restrict__ W_ft, const float* __restrict__ W_fft,
                    unsigned short* __restrict__ comb, int n8)
{
    int i = blockIdx.x * 256 + threadIdx.x;   // 8-element group index
    if (i >= n8) return;
    const int f    = i >> 6;                  // 64 groups of 8 per 512-col row
    const int gcol = (i & 63) * 8;
    const int base = i * 8;
    const int vrow = (f % FV) * FT + gcol;

    const float4 a0 = *(const float4*)(W_ft  + base);
    const float4 a1 = *(const float4*)(W_ft  + base + 4);
    const float4 b0 = *(const float4*)(W_fft + vrow);
    const float4 b1 = *(const float4*)(W_fft + vrow + 4);

    ushort8_t u;
    u[0] = f2bf(a0.x + b0.x); u[1] = f2bf(a0.y + b0.y);
    u[2] = f2bf(a0.z + b0.z); u[3] = f2bf(a0.w + b0.w);
    u[4] = f2bf(a1.x + b1.x); u[5] = f2bf(a1.y + b1.y);
    u[6] = f2bf(a1.z + b1.z); u[7] = f2bf(a1.w + b1.w);
    *(ushort8_t*)(comb + base) = u;
}

// ---- main kernel: combined-table bf16 gather ----
__global__ __launch_bounds__(THREADS)
void nnue_comb_kernel(const float* __restrict__ values,
                      const unsigned short* __restrict__ Wc,
                      const float* __restrict__ ft_b,
                      const float* __restrict__ fft_b,
                      const float* __restrict__ W_out,
                      const float* __restrict__ out_b,
                      const int*   __restrict__ seg_start,
                      const int*   __restrict__ stm_feat,
                      const int*   __restrict__ nstm_feat,
                      float* __restrict__ out)
{
    const int b    = blockIdx.x;
    const int t    = threadIdx.x;
    const int w    = t >> 6;       // wave 0 / 1
    const int lane = t & 63;
    const int col  = lane * 8;     // 8 columns per lane

    const int seg_lo = seg_start[b];
    const int seg_hi = seg_start[b + 1];

    __shared__ int   sh_off_s[CHUNK];
    __shared__ int   sh_off_n[CHUNK];
    __shared__ float sh_v    [CHUNK];
    __shared__ float sh_comb [2][FT];   // wave-1 partials (stm, nstm)

    float acc_s[8] = {0,0,0,0,0,0,0,0};
    float acc_n[8] = {0,0,0,0,0,0,0,0};

    for (int base = seg_lo; base < seg_hi; base += CHUNK) {
        const int cnt = min(CHUNK, seg_hi - base);
        __syncthreads();
        if (t < cnt) {
            sh_off_s[t] = stm_feat [base + t] * FT;
            sh_off_n[t] = nstm_feat[base + t] * FT;
            sh_v    [t] = values[base + t];
        }
        __syncthreads();

        // this wave handles entries j == w (mod 2); simple body (R3 lesson)
        #pragma unroll 4
        for (int j = w; j < cnt; j += 2) {
            const float v = sh_v[j];
            const ushort8_t a = *(const ushort8_t*)(Wc + sh_off_s[j] + col);
            const ushort8_t c = *(const ushort8_t*)(Wc + sh_off_n[j] + col);
            #pragma unroll
            for (int k = 0; k < 8; ++k) {
                acc_s[k] = fmaf(bf2f(a[k]), v, acc_s[k]);
                acc_n[k] = fmaf(bf2f(c[k]), v, acc_n[k]);
            }
        }
    }

    // combine the two waves' partials through LDS
    __syncthreads();
    if (w == 1) {
        #pragma unroll
        for (int k = 0; k < 8; ++k) {
            sh_comb[0][col + k] = acc_s[k];
            sh_comb[1][col + k] = acc_n[k];
        }
    }
    __syncthreads();

    if (w == 0) {
        #pragma unroll
        for (int k = 0; k < 8; ++k) {
            acc_s[k] += sh_comb[0][col + k];
            acc_n[k] += sh_comb[1][col + k];
        }

        const float4 fb0 = *(const float4*)(ft_b  + col);
        const float4 fb1 = *(const float4*)(ft_b  + col + 4);
        const float4 vb0 = *(const float4*)(fft_b + col);
        const float4 vb1 = *(const float4*)(fft_b + col + 4);
        const float4 ws0 = *(const float4*)(W_out + col);
        const float4 ws1 = *(const float4*)(W_out + col + 4);
        const float4 wn0 = *(const float4*)(W_out + FT + col);
        const float4 wn1 = *(const float4*)(W_out + FT + col + 4);

        const float bias[8] = { fb0.x + vb0.x, fb0.y + vb0.y, fb0.z + vb0.z, fb0.w + vb0.w,
                                fb1.x + vb1.x, fb1.y + vb1.y, fb1.z + vb1.z, fb1.w + vb1.w };
        const float wos[8]  = { ws0.x, ws0.y, ws0.z, ws0.w, ws1.x, ws1.y, ws1.z, ws1.w };
        const float won[8]  = { wn0.x, wn0.y, wn0.z, wn0.w, wn1.x, wn1.y, wn1.z, wn1.w };

        float partial = 0.f;
        #pragma unroll
        for (int k = 0; k < 8; ++k) {
            float hs = fminf(fmaxf(acc_s[k] + bias[k], 0.f), 1.f);
            float hn = fminf(fmaxf(acc_n[k] + bias[k], 0.f), 1.f);
            partial = fmaf(hs, wos[k], partial);
            partial = fmaf(hn, won[k], partial);
        }

        #pragma unroll
        for (int off = 32; off > 0; off >>= 1)
            partial += __shfl_down(partial, off, 64);

        if (lane == 0)
            out[b] = 1.0f / (1.0f + expf(-(partial + out_b[0])));
    }
}

// ---- f32 fallback (Round-2 kernel) if ws too small ----
__global__ __launch_bounds__(THREADS)
void nnue_f32_kernel(const float* __restrict__ values,
                     const float* __restrict__ W_ft,
                     const float* __restrict__ ft_b,
                     const float* __restrict__ W_fft,
                     const float* __restrict__ fft_b,
                     const float* __restrict__ W_out,
                     const float* __restrict__ out_b,
                     const int*   __restrict__ batch_ids,
                     const int*   __restrict__ stm_feat,
                     const int*   __restrict__ nstm_feat,
                     int nnz,
                     float* __restrict__ out)
{
    const int b   = blockIdx.x;
    const int t   = threadIdx.x;
    const int col = t * 4;

    int lo0 = 0, hi0 = nnz;
    while (lo0 < hi0) {
        int mid = (lo0 + hi0) >> 1;
        if (batch_ids[mid] < b) lo0 = mid + 1; else hi0 = mid;
    }
    int lo1 = lo0, hi1 = nnz;
    while (lo1 < hi1) {
        int mid = (lo1 + hi1) >> 1;
        if (batch_ids[mid] < b + 1) lo1 = mid + 1; else hi1 = mid;
    }
    const int seg_lo = lo0, seg_hi = lo1;

    __shared__ int   sh_off_s [CHUNK];
    __shared__ int   sh_off_sv[CHUNK];
    __shared__ int   sh_off_n [CHUNK];
    __shared__ int   sh_off_nv[CHUNK];
    __shared__ float sh_v     [CHUNK];

    float4 acc_s = make_float4(0.f, 0.f, 0.f, 0.f);
    float4 acc_n = make_float4(0.f, 0.f, 0.f, 0.f);

    for (int base = seg_lo; base < seg_hi; base += CHUNK) {
        const int cnt = min(CHUNK, seg_hi - base);
        __syncthreads();
        if (t < cnt) {
            int fs = stm_feat[base + t];
            int fn = nstm_feat[base + t];
            sh_off_s [t] = fs * FT;
            sh_off_sv[t] = (fs % FV) * FT;
            sh_off_n [t] = fn * FT;
            sh_off_nv[t] = (fn % FV) * FT;
            sh_v     [t] = values[base + t];
        }
        __syncthreads();

        #pragma unroll 2
        for (int j = 0; j < cnt; ++j) {
            const float v = sh_v[j];
            const float4 a  = *(const float4*)(W_ft  + sh_off_s [j] + col);
            const float4 av = *(const float4*)(W_fft + sh_off_sv[j] + col);
            const float4 c  = *(const float4*)(W_ft  + sh_off_n [j] + col);
            const float4 cv = *(const float4*)(W_fft + sh_off_nv[j] + col);
            acc_s.x = fmaf(a.x + av.x, v, acc_s.x);
            acc_s.y = fmaf(a.y + av.y, v, acc_s.y);
            acc_s.z = fmaf(a.z + av.z, v, acc_s.z);
            acc_s.w = fmaf(a.w + av.w, v, acc_s.w);
            acc_n.x = fmaf(c.x + cv.x, v, acc_n.x);
            acc_n.y = fmaf(c.y + cv.y, v, acc_n.y);
            acc_n.z = fmaf(c.z + cv.z, v, acc_n.z);
            acc_n.w = fmaf(c.w + cv.w, v, acc_n.w);
        }
    }

    const float4 fb  = *(const float4*)(ft_b  + col);
    const float4 vb  = *(const float4*)(fft_b + col);
    const float4 wos = *(const float4*)(W_out + col);
    const float4 won = *(const float4*)(W_out + FT + col);

    float partial = 0.f;
    {
        float h;
        h = fminf(fmaxf(acc_s.x + fb.x + vb.x, 0.f), 1.f); partial = fmaf(h, wos.x, partial);
        h = fminf(fmaxf(acc_s.y + fb.y + vb.y, 0.f), 1.f); partial = fmaf(h, wos.y, partial);
        h = fminf(fmaxf(acc_s.z + fb.z + vb.z, 0.f), 1.f); partial = fmaf(h, wos.z, partial);
        h = fminf(fmaxf(acc_s.w + fb.w + vb.w, 0.f), 1.f); partial = fmaf(h, wos.w, partial);
        h = fminf(fmaxf(acc_n.x + fb.x + vb.x, 0.f), 1.f); partial = fmaf(h, won.x, partial);
        h = fminf(fmaxf(acc_n.y + fb.y + vb.y, 0.f), 1.f); partial = fmaf(h, won.y, partial);
        h = fminf(fmaxf(acc_n.z + fb.z + vb.z, 0.f), 1.f); partial = fmaf(h, won.z, partial);
        h = fminf(fmaxf(acc_n.w + fb.w + vb.w, 0.f), 1.f); partial = fmaf(h, won.w, partial);
    }

    #pragma unroll
    for (int off = 32; off > 0; off >>= 1)
        partial += __shfl_down(partial, off, 64);

    __shared__ float wave_sum[THREADS / 64];
    if ((t & 63) == 0) wave_sum[t >> 6] = partial;
    __syncthreads();
    if (t == 0) {
        float s = wave_sum[0] + wave_sum[1] + out_b[0];
        out[b] = 1.0f / (1.0f + expf(-s));
    }
}

extern "C" void kernel_launch(void* const* d_in, const int* in_sizes, int n_in,
                              void* d_out, int out_size, void* d_ws, size_t ws_size,
                              hipStream_t stream) {
    const float* values    = (const float*)d_in[0];
    const float* W_ft      = (const float*)d_in[1];
    const float* ft_b      = (const float*)d_in[2];
    const float* W_fft     = (const float*)d_in[3];
    const float* fft_b     = (const float*)d_in[4];
    const float* W_out     = (const float*)d_in[5];
    const float* out_b     = (const float*)d_in[6];
    const int*   batch_ids = (const int*)d_in[7];
    const int*   stm_feat  = (const int*)d_in[8];
    const int*   nstm_feat = (const int*)d_in[9];

    const int nnz  = in_sizes[0];
    const int B    = out_size;
    const int n_ft = in_sizes[1];   // F_FULL*FT elements

    // workspace layout: [comb table: n_ft ushort][seg_start: B+1 int]
    const size_t comb_bytes = (size_t)n_ft * sizeof(unsigned short);
    const size_t need = comb_bytes + (size_t)(B + 1) * sizeof(int);

    if (ws_size >= need) {
        unsigned short* comb = (unsigned short*)d_ws;
        int* seg_start = (int*)((char*)d_ws + comb_bytes);

        const int n8    = n_ft / 8;
        const int cgrid = (n8 + 255) / 256;
        const int bgrid = (B + 1 + 255) / 256;

        bounds_kernel<<<bgrid, 256, 0, stream>>>(batch_ids, nnz, B, seg_start);
        convert_kernel<<<cgrid, 256, 0, stream>>>(W_ft, W_fft, comb, n8);
        nnue_comb_kernel<<<B, THREADS, 0, stream>>>(
            values, comb, ft_b, fft_b, W_out, out_b,
            seg_start, stm_feat, nstm_feat, (float*)d_out);
    } else {
        nnue_f32_kernel<<<B, THREADS, 0, stream>>>(
            values, W_ft, ft_b, W_fft, fft_b, W_out, out_b,
            batch_ids, stm_feat, nstm_feat, nnz, (float*)d_out);
    }
}